// Round 5
// baseline (194.290 us; speedup 1.0000x reference)
//
#include <hip/hip_runtime.h>
#include <stdint.h>

#define B_  2
#define S_  768
#define D_  768
#define H_  8
#define DH_ 96

typedef unsigned short ushort_t;
typedef __bf16 bf16x8 __attribute__((ext_vector_type(8)));
typedef float  f32x4  __attribute__((ext_vector_type(4)));
typedef unsigned short u16x8 __attribute__((ext_vector_type(8)));

__device__ inline ushort_t f2bf(float f) {
    union { float f; unsigned int u; } v; v.f = f;
    unsigned int u = v.u;
    unsigned int r = u + 0x7fffu + ((u >> 16) & 1u);
    return (ushort_t)(r >> 16);
}
__device__ inline float bf2f(ushort_t u) {
    union { unsigned int i; float f; } c; c.i = ((unsigned int)u) << 16;
    return c.f;
}
// convert 8 f32 -> 8 bf16, single b128 LDS store
__device__ inline void cvt8st(ushort_t* dst, float4 a, float4 b) {
    u16x8 o;
    o[0] = f2bf(a.x); o[1] = f2bf(a.y); o[2] = f2bf(a.z); o[3] = f2bf(a.w);
    o[4] = f2bf(b.x); o[5] = f2bf(b.y); o[6] = f2bf(b.z); o[7] = f2bf(b.w);
    *(u16x8*)dst = o;
}

// ---------------------------------------------------------------- QKV GEMM
// A = X f32 [1536,768]; B = Wq|Wk|Wv f32 (block-uniform select, 64-col tiles
// never cross a 768 boundary). f32->bf16 convert in staging regs. Software-
// pipelined: load(c+1) -> consume(c) -> ds_write(c+1) -> barrier.
__global__ __launch_bounds__(256) void k_qkv(
        const float* __restrict__ X,
        const float* __restrict__ Wq, const float* __restrict__ Wk,
        const float* __restrict__ Wv,
        const float* __restrict__ bq, const float* __restrict__ bk,
        const float* __restrict__ bv,
        ushort_t* __restrict__ Qb, ushort_t* __restrict__ Kb,
        ushort_t* __restrict__ Vtb) {
    __shared__ __align__(16) ushort_t As[2][64 * 32];
    __shared__ __align__(16) ushort_t Bs[2][64 * 32];
    const int tid = threadIdx.x, lane = tid & 63, wave = tid >> 6;
    const int wm = (wave >> 1) * 32, wn = (wave & 1) * 32;
    const int fr = lane & 15, fk = (lane >> 4) * 8, frg4 = (lane >> 4) * 4;
    const int m0 = blockIdx.y * 64, n0 = blockIdx.x * 64;
    const int g = n0 / D_, nb = n0 - g * D_;
    const float* W      = (g == 0) ? Wq : (g == 1) ? Wk : Wv;
    const float* bias_p = (g == 0) ? bq : (g == 1) ? bk : bv;
    const int sr = wave * 16 + (lane >> 2), sc = (lane & 3) * 8;
    const float* Ap = X + (size_t)(m0 + sr) * D_ + sc;
    const float* Bp = W + (size_t)(nb + sr) * D_ + sc;
    ushort_t* Asd = &As[0][sr * 32 + sc];   // staged dst (per-buf offset below)
    ushort_t* Bsd = &Bs[0][sr * 32 + sc];
    const int bufstride = 64 * 32;

    float4 a0r, a1r, b0r, b1r;
    a0r = *(const float4*)(Ap);     a1r = *(const float4*)(Ap + 4);
    b0r = *(const float4*)(Bp);     b1r = *(const float4*)(Bp + 4);
    cvt8st(Asd, a0r, a1r);
    cvt8st(Bsd, b0r, b1r);
    __syncthreads();

    f32x4 acc[2][2];
    #pragma unroll
    for (int i = 0; i < 2; i++)
        #pragma unroll
        for (int j = 0; j < 2; j++) acc[i][j] = (f32x4){0.f, 0.f, 0.f, 0.f};

    for (int c = 0; c < 24; ++c) {
        if (c < 23) {
            const float* Apn = Ap + (c + 1) * 32;
            const float* Bpn = Bp + (c + 1) * 32;
            a0r = *(const float4*)(Apn);     a1r = *(const float4*)(Apn + 4);
            b0r = *(const float4*)(Bpn);     b1r = *(const float4*)(Bpn + 4);
        }
        const ushort_t* Ab = As[c & 1];
        const ushort_t* Bb = Bs[c & 1];
        bf16x8 a0 = *(const bf16x8*)&Ab[(wm      + fr) * 32 + fk];
        bf16x8 a1 = *(const bf16x8*)&Ab[(wm + 16 + fr) * 32 + fk];
        bf16x8 b0 = *(const bf16x8*)&Bb[(wn      + fr) * 32 + fk];
        bf16x8 b1 = *(const bf16x8*)&Bb[(wn + 16 + fr) * 32 + fk];
        acc[0][0] = __builtin_amdgcn_mfma_f32_16x16x32_bf16(a0, b0, acc[0][0], 0, 0, 0);
        acc[0][1] = __builtin_amdgcn_mfma_f32_16x16x32_bf16(a0, b1, acc[0][1], 0, 0, 0);
        acc[1][0] = __builtin_amdgcn_mfma_f32_16x16x32_bf16(a1, b0, acc[1][0], 0, 0, 0);
        acc[1][1] = __builtin_amdgcn_mfma_f32_16x16x32_bf16(a1, b1, acc[1][1], 0, 0, 0);
        if (c < 23) {
            int nb2 = (c + 1) & 1;
            cvt8st(Asd + nb2 * bufstride, a0r, a1r);
            cvt8st(Bsd + nb2 * bufstride, b0r, b1r);
        }
        __syncthreads();
    }
    // epilogue
    #pragma unroll
    for (int ni = 0; ni < 2; ni++) {
        int d768 = nb + wn + ni * 16 + fr;
        int h = d768 / DH_, d = d768 - h * DH_;
        float bias = bias_p[d768];
        #pragma unroll
        for (int mi = 0; mi < 2; mi++) {
            #pragma unroll
            for (int r = 0; r < 4; r++) {
                int grow = m0 + wm + mi * 16 + frg4 + r;
                int b = grow / S_, s = grow - b * S_;
                ushort_t ob = f2bf(acc[mi][ni][r] + bias);
                int bh = b * H_ + h;
                if (g == 0)      Qb[((size_t)bh * S_ + s) * DH_ + d] = ob;
                else if (g == 1) Kb[((size_t)bh * S_ + s) * DH_ + d] = ob;
                else             Vtb[((size_t)bh * DH_ + d) * S_ + s] = ob;
            }
        }
    }
}

// ---------------------------------------------------------------- qcoef
__global__ __launch_bounds__(256) void k_qcoef(
        const ushort_t* __restrict__ Qb,
        const float* __restrict__ Wd, const float* __restrict__ bd,
        const float* __restrict__ Wa, const float* __restrict__ ba,
        float* __restrict__ qcoef) {
    const int wave = threadIdx.x >> 6, lane = threadIdx.x & 63;
    const int row = blockIdx.x * 4 + wave;
    const ushort_t* q = Qb + (size_t)row * DH_;
    float e0 = bf2f(q[lane]);
    float c0 = e0 * Wd[lane];
    float c1 = e0 * Wa[lane];
    float c2 = e0 * (bd[lane] + ba[lane]);
    if (lane < 32) {
        int d = 64 + lane;
        float e1 = bf2f(q[d]);
        c0 += e1 * Wd[d];
        c1 += e1 * Wa[d];
        c2 += e1 * (bd[d] + ba[d]);
    }
    #pragma unroll
    for (int o = 32; o > 0; o >>= 1) {
        c0 += __shfl_down(c0, o);
        c1 += __shfl_down(c1, o);
        c2 += __shfl_down(c2, o);
    }
    if (lane == 0) {
        qcoef[row * 3 + 0] = c0;
        qcoef[row * 3 + 1] = c1;
        qcoef[row * 3 + 2] = c2;
    }
}

// ---------------------------------------------------------------- fused flash v3
// Same algorithm as v2 (XCD-pinned grid 384, 32 q-rows/block) but both loops are
// software-pipelined: load(s+1) regs -> consume(s) -> ds_write(s+1) -> barrier.
// Mask pre-staged to LDS.
#define L1B 29696   // Ks 12288 + Dd 8704 + Da 8704
__global__ __launch_bounds__(256) void k_flash(
        const ushort_t* __restrict__ Qb, const ushort_t* __restrict__ Kb,
        const ushort_t* __restrict__ Vtb, const float* __restrict__ qcoef,
        const float* __restrict__ distm, const float* __restrict__ angm,
        const float* __restrict__ mask,
        float* __restrict__ probs, ushort_t* __restrict__ Ctxb) {
    __shared__ __align__(16) char sm[2 * L1B + 640 + 3072];
    float* mstat = (float*)(sm + 2 * L1B);          // [2][32]
    float* lstat = (float*)(sm + 2 * L1B + 256);    // [2][32]
    float* linv  = (float*)(sm + 2 * L1B + 512);    // [32]
    float* Ms    = (float*)(sm + 2 * L1B + 640);    // [768] (1-mask)*-1e4
    const int idx = blockIdx.x;
    const int h = idx / 48, rem = idx - h * 48;
    const int b = rem / 24, r0 = (rem - b * 24) * 32;
    const int bh = b * H_ + h;
    const int tid = threadIdx.x, lane = tid & 63, w = tid >> 6;
    const int frn = lane & 15, fko = (lane >> 4) * 8, frg4 = (lane >> 4) * 4;
    const int rg = w & 1, cp = w >> 1;
    const ushort_t* Qbh = Qb + (size_t)bh * S_ * DH_;
    const ushort_t* Kbh = Kb + (size_t)bh * S_ * DH_;
    const ushort_t* Vbh = Vtb + (size_t)bh * DH_ * S_;

    // mask pre-stage
    Ms[tid]       = (1.0f - mask[b * S_ + tid])       * -10000.0f;
    Ms[tid + 256] = (1.0f - mask[b * S_ + tid + 256]) * -10000.0f;
    Ms[tid + 512] = (1.0f - mask[b * S_ + tid + 512]) * -10000.0f;

    // Q fragments + per-row coefs
    bf16x8 aq[3];
    {
        const ushort_t* qp = Qbh + (size_t)(r0 + rg * 16 + frn) * DH_ + fko;
        aq[0] = *(const bf16x8*)qp;
        aq[1] = *(const bf16x8*)(qp + 32);
        aq[2] = *(const bf16x8*)(qp + 64);
    }
    float qc0[4], qc1[4], qc2[4];
    #pragma unroll
    for (int r = 0; r < 4; r++) {
        const float* qp = qcoef + ((size_t)bh * S_ + r0 + rg * 16 + frg4 + r) * 3;
        qc0[r] = qp[0]; qc1[r] = qp[1]; qc2[r] = qp[2];
    }
    const float isq = 0.10206207261596577f;   // 1/sqrt(96)

    // staging geometry
    const int krow = tid / 12,        kcc = (tid - krow * 12) * 8;        // K part 0
    const int krow1 = (tid + 256) / 12, kcc1 = ((tid + 256) % 12) * 8;    // part 1
    const int krow2 = (tid + 512) / 12, kcc2 = ((tid + 512) % 12) * 8;    // part 2
    const int drow = tid >> 4,  dc4 = (tid & 15) * 4;                     // d/a part 0
    const int drow1 = (tid + 256) >> 4, dc41 = ((tid + 256) & 15) * 4;    // part 1

    uint4 kr0, kr1, kr2; float4 dr0, dr1, ar0, ar1;
    // ---- load chunk 0
    {
        kr0 = *(const uint4*)(Kbh + (size_t)krow  * DH_ + kcc);
        kr1 = *(const uint4*)(Kbh + (size_t)krow1 * DH_ + kcc1);
        kr2 = *(const uint4*)(Kbh + (size_t)krow2 * DH_ + kcc2);
        size_t s0 = ((size_t)b * S_ + r0 + drow)  * S_ + dc4;
        size_t s1 = ((size_t)b * S_ + r0 + drow1) * S_ + dc41;
        dr0 = *(const float4*)(distm + s0);  dr1 = *(const float4*)(distm + s1);
        ar0 = *(const float4*)(angm  + s0);  ar1 = *(const float4*)(angm  + s1);
    }
    // ---- write chunk 0 -> buf0
    {
        ushort_t* Ks = (ushort_t*)sm;
        float* Dd = (float*)(sm + 12288);
        float* Da = (float*)(sm + 20992);
        *(uint4*)(Ks + krow * 96 + kcc)   = kr0;
        *(uint4*)(Ks + krow1 * 96 + kcc1) = kr1;
        *(uint4*)(Ks + krow2 * 96 + kcc2) = kr2;
        *(float4*)(Dd + drow * 68 + dc4)   = dr0;
        *(float4*)(Dd + drow1 * 68 + dc41) = dr1;
        *(float4*)(Da + drow * 68 + dc4)   = ar0;
        *(float4*)(Da + drow1 * 68 + dc41) = ar1;
    }
    __syncthreads();

    // ---- loop 1: scores in regs (pipelined)
    f32x4 acc[24];
    for (int c = 0; c < 12; ++c) {
        if (c < 11) {
            const ushort_t* kb = Kbh + (size_t)(c + 1) * 64 * DH_;
            kr0 = *(const uint4*)(kb + (size_t)krow  * DH_ + kcc);
            kr1 = *(const uint4*)(kb + (size_t)krow1 * DH_ + kcc1);
            kr2 = *(const uint4*)(kb + (size_t)krow2 * DH_ + kcc2);
            size_t s0 = ((size_t)b * S_ + r0 + drow)  * S_ + (c + 1) * 64 + dc4;
            size_t s1 = ((size_t)b * S_ + r0 + drow1) * S_ + (c + 1) * 64 + dc41;
            dr0 = *(const float4*)(distm + s0);  dr1 = *(const float4*)(distm + s1);
            ar0 = *(const float4*)(angm  + s0);  ar1 = *(const float4*)(angm  + s1);
        }
        char* bufc = sm + (c & 1) * L1B;
        const ushort_t* Ks = (const ushort_t*)bufc;
        const float* Dd = (const float*)(bufc + 12288);
        const float* Da = (const float*)(bufc + 20992);
        #pragma unroll
        for (int tt = 0; tt < 2; ++tt) {
            const ushort_t* kp = Ks + (cp * 32 + tt * 16 + frn) * 96 + fko;
            f32x4 ca = (f32x4){0.f, 0.f, 0.f, 0.f};
            ca = __builtin_amdgcn_mfma_f32_16x16x32_bf16(aq[0], *(const bf16x8*)kp, ca, 0, 0, 0);
            ca = __builtin_amdgcn_mfma_f32_16x16x32_bf16(aq[1], *(const bf16x8*)(kp + 32), ca, 0, 0, 0);
            ca = __builtin_amdgcn_mfma_f32_16x16x32_bf16(aq[2], *(const bf16x8*)(kp + 64), ca, 0, 0, 0);
            int jl = cp * 32 + tt * 16 + frn;
            float mb = Ms[c * 64 + jl];
            #pragma unroll
            for (int r = 0; r < 4; ++r) {
                int rl = rg * 16 + frg4 + r;
                acc[c * 2 + tt][r] = ca[r] * isq + Dd[rl * 68 + jl] * qc0[r]
                                   + Da[rl * 68 + jl] * qc1[r] + qc2[r] + mb;
            }
        }
        if (c < 11) {
            char* bufn = sm + ((c + 1) & 1) * L1B;
            ushort_t* Ksn = (ushort_t*)bufn;
            float* Ddn = (float*)(bufn + 12288);
            float* Dan = (float*)(bufn + 20992);
            *(uint4*)(Ksn + krow * 96 + kcc)   = kr0;
            *(uint4*)(Ksn + krow1 * 96 + kcc1) = kr1;
            *(uint4*)(Ksn + krow2 * 96 + kcc2) = kr2;
            *(float4*)(Ddn + drow * 68 + dc4)   = dr0;
            *(float4*)(Ddn + drow1 * 68 + dc41) = dr1;
            *(float4*)(Dan + drow * 68 + dc4)   = ar0;
            *(float4*)(Dan + drow1 * 68 + dc41) = ar1;
        }
        __syncthreads();
    }

    // ---- softmax (exact)
    float mx[4] = {-1e30f, -1e30f, -1e30f, -1e30f};
    #pragma unroll
    for (int t = 0; t < 24; t++)
        #pragma unroll
        for (int r = 0; r < 4; r++) mx[r] = fmaxf(mx[r], acc[t][r]);
    #pragma unroll
    for (int o = 1; o < 16; o <<= 1)
        #pragma unroll
        for (int r = 0; r < 4; r++) mx[r] = fmaxf(mx[r], __shfl_xor(mx[r], o));
    if (frn == 0)
        #pragma unroll
        for (int r = 0; r < 4; r++) mstat[cp * 32 + rg * 16 + frg4 + r] = mx[r];
    __syncthreads();
    float mf[4], sum[4] = {0.f, 0.f, 0.f, 0.f};
    #pragma unroll
    for (int r = 0; r < 4; r++) {
        int rl = rg * 16 + frg4 + r;
        mf[r] = fmaxf(mstat[rl], mstat[32 + rl]);
    }
    #pragma unroll
    for (int t = 0; t < 24; t++)
        #pragma unroll
        for (int r = 0; r < 4; r++) {
            float e = __expf(acc[t][r] - mf[r]);
            acc[t][r] = e;
            sum[r] += e;
        }
    #pragma unroll
    for (int o = 1; o < 16; o <<= 1)
        #pragma unroll
        for (int r = 0; r < 4; r++) sum[r] += __shfl_xor(sum[r], o);
    if (frn == 0)
        #pragma unroll
        for (int r = 0; r < 4; r++) lstat[cp * 32 + rg * 16 + frg4 + r] = sum[r];
    __syncthreads();
    float inv[4];
    #pragma unroll
    for (int r = 0; r < 4; r++) {
        int rl = rg * 16 + frg4 + r;
        inv[r] = 1.0f / (lstat[rl] + lstat[32 + rl]);
        if (cp == 0 && frn == 0) linv[rl] = inv[r];
    }
    __syncthreads();

    // ---- loop 2: probs write + P@V (pipelined)
    f32x4 accO[3];
    #pragma unroll
    for (int i = 0; i < 3; i++) accO[i] = (f32x4){0.f, 0.f, 0.f, 0.f};
    const int prow = tid >> 3, pc8 = (tid & 7) * 4;
    float* pout = probs + ((size_t)bh * S_ + r0 + prow) * S_;
    const int vrow = tid >> 2, vcv = (tid & 3) * 8;
    const int vrow2 = (tid + 256) >> 2, vcv2 = ((tid + 256) & 3) * 8;
    const bool hasv2 = (tid < 128);
    uint4 vr0, vr1;
    // load V(0)
    vr0 = *(const uint4*)(Vbh + (size_t)vrow * S_ + vcv);
    if (hasv2) vr1 = *(const uint4*)(Vbh + (size_t)vrow2 * S_ + vcv2);
    // write V(0), Ps(0) -> buf0
    {
        ushort_t* Vs = (ushort_t*)(sm);
        ushort_t* Ps = (ushort_t*)(sm + 15360);
        *(uint4*)(Vs + vrow * 40 + vcv) = vr0;
        if (hasv2) *(uint4*)(Vs + vrow2 * 40 + vcv2) = vr1;
        if (cp == 0) {
            #pragma unroll
            for (int tt = 0; tt < 2; ++tt)
                #pragma unroll
                for (int r = 0; r < 4; ++r)
                    Ps[(rg * 16 + frg4 + r) * 40 + tt * 16 + frn] = f2bf(acc[tt][r]);
        }
    }
    __syncthreads();
    for (int s = 0; s < 24; ++s) {
        if (s < 23) {
            vr0 = *(const uint4*)(Vbh + (size_t)vrow * S_ + (s + 1) * 32 + vcv);
            if (hasv2) vr1 = *(const uint4*)(Vbh + (size_t)vrow2 * S_ + (s + 1) * 32 + vcv2);
        }
        const ushort_t* Vs = (const ushort_t*)(sm + (s & 1) * 7680);
        const ushort_t* Ps = (const ushort_t*)(sm + 15360 + (s & 1) * 2560);
        {
            float iv = linv[prow];
            float4 p4;
            p4.x = bf2f(Ps[prow * 40 + pc8 + 0]) * iv;
            p4.y = bf2f(Ps[prow * 40 + pc8 + 1]) * iv;
            p4.z = bf2f(Ps[prow * 40 + pc8 + 2]) * iv;
            p4.w = bf2f(Ps[prow * 40 + pc8 + 3]) * iv;
            *(float4*)(pout + s * 32 + pc8) = p4;
        }
        bf16x8 a = *(const bf16x8*)&Ps[(rg * 16 + frn) * 40 + fko];
        #pragma unroll
        for (int nt = 0; nt < 3; ++nt) {
            bf16x8 v = *(const bf16x8*)&Vs[(cp * 48 + nt * 16 + frn) * 40 + fko];
            accO[nt] = __builtin_amdgcn_mfma_f32_16x16x32_bf16(a, v, accO[nt], 0, 0, 0);
        }
        if (s < 23) {
            ushort_t* Vsn = (ushort_t*)(sm + ((s + 1) & 1) * 7680);
            ushort_t* Psn = (ushort_t*)(sm + 15360 + ((s + 1) & 1) * 2560);
            *(uint4*)(Vsn + vrow * 40 + vcv) = vr0;
            if (hasv2) *(uint4*)(Vsn + vrow2 * 40 + vcv2) = vr1;
            if (cp == ((s + 1) & 1)) {
                #pragma unroll
                for (int tt = 0; tt < 2; ++tt)
                    #pragma unroll
                    for (int r = 0; r < 4; ++r)
                        Psn[(rg * 16 + frg4 + r) * 40 + tt * 16 + frn] =
                            f2bf(acc[((s + 1) & ~1) + tt][r]);
            }
        }
        __syncthreads();
    }
    // ---- ctx epilogue
    #pragma unroll
    for (int nt = 0; nt < 3; ++nt) {
        int col = h * DH_ + cp * 48 + nt * 16 + frn;
        #pragma unroll
        for (int r = 0; r < 4; ++r) {
            int row = r0 + rg * 16 + frg4 + r;
            Ctxb[((size_t)(b * S_ + row)) * D_ + col] = f2bf(accO[nt][r] * inv[r]);
        }
    }
}

// ---------------------------------------------------------------- out GEMM + bias + residual
// A = Ctxb bf16; B = Wo f32 (convert in staging). Pipelined like k_qkv.
__global__ __launch_bounds__(256) void k_out(
        const ushort_t* __restrict__ Ctxb, const float* __restrict__ Wo,
        const float* __restrict__ bo, const float* __restrict__ hidden,
        float* __restrict__ xbuf) {
    __shared__ __align__(16) ushort_t As[2][64 * 32];
    __shared__ __align__(16) ushort_t Bs[2][64 * 32];
    const int tid = threadIdx.x, lane = tid & 63, wave = tid >> 6;
    const int wm = (wave >> 1) * 32, wn = (wave & 1) * 32;
    const int fr = lane & 15, fk = (lane >> 4) * 8, frg4 = (lane >> 4) * 4;
    const int m0 = blockIdx.y * 64, n0 = blockIdx.x * 64;
    const int sr = wave * 16 + (lane >> 2), sc = (lane & 3) * 8;
    const ushort_t* Ap = Ctxb + (size_t)(m0 + sr) * D_ + sc;
    const float*    Bp = Wo   + (size_t)(n0 + sr) * D_ + sc;
    const int bufstride = 64 * 32;
    ushort_t* Asd = &As[0][sr * 32 + sc];
    ushort_t* Bsd = &Bs[0][sr * 32 + sc];

    uint4 arr; float4 b0r, b1r;
    arr = *(const uint4*)(Ap);
    b0r = *(const float4*)(Bp);  b1r = *(const float4*)(Bp + 4);
    *(uint4*)Asd = arr;
    cvt8st(Bsd, b0r, b1r);
    __syncthreads();

    f32x4 acc[2][2];
    #pragma unroll
    for (int i = 0; i < 2; i++)
        #pragma unroll
        for (int j = 0; j < 2; j++) acc[i][j] = (f32x4){0.f, 0.f, 0.f, 0.f};

    for (int c = 0; c < 24; ++c) {
        if (c < 23) {
            arr = *(const uint4*)(Ap + (c + 1) * 32);
            b0r = *(const float4*)(Bp + (c + 1) * 32);
            b1r = *(const float4*)(Bp + (c + 1) * 32 + 4);
        }
        const ushort_t* Ab = As[c & 1];
        const ushort_t* Bb = Bs[c & 1];
        bf16x8 a0 = *(const bf16x8*)&Ab[(wm      + fr) * 32 + fk];
        bf16x8 a1 = *(const bf16x8*)&Ab[(wm + 16 + fr) * 32 + fk];
        bf16x8 b0 = *(const bf16x8*)&Bb[(wn      + fr) * 32 + fk];
        bf16x8 b1 = *(const bf16x8*)&Bb[(wn + 16 + fr) * 32 + fk];
        acc[0][0] = __builtin_amdgcn_mfma_f32_16x16x32_bf16(a0, b0, acc[0][0], 0, 0, 0);
        acc[0][1] = __builtin_amdgcn_mfma_f32_16x16x32_bf16(a0, b1, acc[0][1], 0, 0, 0);
        acc[1][0] = __builtin_amdgcn_mfma_f32_16x16x32_bf16(a1, b0, acc[1][0], 0, 0, 0);
        acc[1][1] = __builtin_amdgcn_mfma_f32_16x16x32_bf16(a1, b1, acc[1][1], 0, 0, 0);
        if (c < 23) {
            int nb2 = (c + 1) & 1;
            *(uint4*)(Asd + nb2 * bufstride) = arr;
            cvt8st(Bsd + nb2 * bufstride, b0r, b1r);
        }
        __syncthreads();
    }
    #pragma unroll
    for (int ni = 0; ni < 2; ni++) {
        int gcol = n0 + wn + ni * 16 + fr;
        float bias = bo[gcol];
        #pragma unroll
        for (int mi = 0; mi < 2; mi++) {
            #pragma unroll
            for (int r = 0; r < 4; r++) {
                int grow = m0 + wm + mi * 16 + frg4 + r;
                xbuf[(size_t)grow * D_ + gcol] =
                    acc[mi][ni][r] + bias + hidden[(size_t)grow * D_ + gcol];
            }
        }
    }
}

// ---------------------------------------------------------------- LayerNorm
__global__ __launch_bounds__(256) void k_ln(
        const float* __restrict__ xbuf, const float* __restrict__ g,
        const float* __restrict__ bb, float* __restrict__ out) {
    const float* x = xbuf + (size_t)blockIdx.x * D_;
    const int t = threadIdx.x;
    float a0 = x[t], a1 = x[t + 256], a2 = x[t + 512];
    float s = a0 + a1 + a2;
    float ss = a0 * a0 + a1 * a1 + a2 * a2;
    __shared__ float r1[4], r2[4];
    #pragma unroll
    for (int o = 32; o > 0; o >>= 1) { s += __shfl_down(s, o); ss += __shfl_down(ss, o); }
    if ((t & 63) == 0) { r1[t >> 6] = s; r2[t >> 6] = ss; }
    __syncthreads();
    float ts = r1[0] + r1[1] + r1[2] + r1[3];
    float tss = r2[0] + r2[1] + r2[2] + r2[3];
    float mu = ts * (1.0f / D_);
    float var = tss * (1.0f / D_) - mu * mu;
    float rstd = rsqrtf(var + 1e-5f);
    float* o = out + (size_t)blockIdx.x * D_;
    o[t]       = (a0 - mu) * rstd * g[t]       + bb[t];
    o[t + 256] = (a1 - mu) * rstd * g[t + 256] + bb[t + 256];
    o[t + 512] = (a2 - mu) * rstd * g[t + 512] + bb[t + 512];
}

// ---------------------------------------------------------------- launch
extern "C" void kernel_launch(void* const* d_in, const int* in_sizes, int n_in,
                              void* d_out, int out_size, void* d_ws, size_t ws_size,
                              hipStream_t stream) {
    const float* X     = (const float*)d_in[0];
    const float* distm = (const float*)d_in[1];
    const float* angm  = (const float*)d_in[2];
    const float* mask  = (const float*)d_in[3];
    const float* Wq    = (const float*)d_in[4];
    const float* bq    = (const float*)d_in[5];
    const float* Wk    = (const float*)d_in[6];
    const float* bk    = (const float*)d_in[7];
    const float* Wv    = (const float*)d_in[8];
    const float* bv    = (const float*)d_in[9];
    const float* Wd    = (const float*)d_in[10];
    const float* bd    = (const float*)d_in[11];
    const float* Wa    = (const float*)d_in[12];
    const float* ba    = (const float*)d_in[13];
    const float* Wo    = (const float*)d_in[14];
    const float* bo    = (const float*)d_in[15];
    const float* ln_g  = (const float*)d_in[16];
    const float* ln_b  = (const float*)d_in[17];

    float* outp  = (float*)d_out;                        // [B,S,D]
    float* probs = (float*)d_out + (size_t)B_ * S_ * D_; // [B,H,S,S]

    char* ws = (char*)d_ws;
    ushort_t* Qb    = (ushort_t*)(ws + 0);          // 2,359,296 B
    ushort_t* Kb    = (ushort_t*)(ws + 2359296);    // 2,359,296 B
    ushort_t* Vtb   = (ushort_t*)(ws + 4718592);    // 2,359,296 B
    ushort_t* Ctxb  = (ushort_t*)(ws + 7077888);    // 2,359,296 B
    float*    qcoef = (float*)   (ws + 9437184);    //   147,456 B
    float*    xbuf  = (float*)   (ws + 9584640);    // 4,718,592 B (end ~14.3 MB)

    k_qkv<<<dim3(36, 24), 256, 0, stream>>>(X, Wq, Wk, Wv, bq, bk, bv, Qb, Kb, Vtb);
    k_qcoef<<<3072, 256, 0, stream>>>(Qb, Wd, bd, Wa, ba, qcoef);
    k_flash<<<384, 256, 0, stream>>>(Qb, Kb, Vtb, qcoef, distm, angm, mask, probs, Ctxb);
    k_out<<<dim3(12, 24), 256, 0, stream>>>(Ctxb, Wo, bo, X, xbuf);
    k_ln<<<1536, 256, 0, stream>>>(xbuf, ln_g, ln_b, outp);
}